// Round 17
// baseline (255.955 us; speedup 1.0000x reference)
//
#include <hip/hip_runtime.h>
#include <hip/hip_bf16.h>
#include <cstddef>

// GNN: dense1+BN+ReLU -> SAGE(mean) -> dense2+BN+ReLU -> SAGE(mean) -> dense_out
// Round 17 = round 16 (validated best, 253.2us) + ONE mechanism test:
//   - STATS fusion removed from dense GEMMs (the post-C-write barrier pair
//     kept blocks alive ~2x past useful work -> 12% occupancy). Dense GEMMs
//     now retire at the C-write (same template path as the validated out
//     layer); stats computed by a standalone bf16 colstats pass (25.6MB read,
//     round-3-validated pattern).
//   - everything else identical to round 16.

#define NN 100000
#define NE 800000
#define EPB 2048                     // edges per hist/scatter block
#define NBLK ((NE + EPB - 1) / EPB)  // 391
#define NBUK ((NN + 511) / 512)      // 196 buckets of 512 nodes
#define BSLACK (512 * 7)             // max pad slack per bucket (x8 padding)
#define CSRCAP (NE + NBUK * BSLACK)  // padded csr upper bound

typedef __attribute__((ext_vector_type(8))) short short8;
typedef __attribute__((ext_vector_type(4))) float f32x4;

__device__ inline unsigned short f2bf(float f) {
    unsigned int u = __float_as_uint(f);
    u += 0x7fff + ((u >> 16) & 1);   // round-to-nearest-even
    return (unsigned short)(u >> 16);
}
__device__ inline float lo16f(unsigned u) { return __uint_as_float(u << 16); }
__device__ inline float hi16f(unsigned u) { return __uint_as_float(u & 0xffff0000u); }

#define GLOAD16(gp, lp)                                                              \
    __builtin_amdgcn_global_load_lds((const __attribute__((address_space(1))) unsigned int*)(gp), \
                                     (__attribute__((address_space(3))) unsigned int*)(lp), 16, 0, 0)

// ---------------- conversions (+ fused stats/sentinel zeroing) ----------------

__global__ __launch_bounds__(256) void wcvt_kernel(const float* W1, const float* Ws1, const float* Wn1,
                                                   const float* W2, const float* Ws2, const float* Wn2,
                                                   const float* W3, unsigned short* out,
                                                   float* stats_z, unsigned int* sent_z) {
    // block 0: zero both layers' stats (512 floats); block 1: zero sentinel row (256B)
    if (blockIdx.x == 0 && threadIdx.x < 128)
        ((float4*)stats_z)[threadIdx.x] = (float4){0.f, 0.f, 0.f, 0.f};
    if (blockIdx.x == 1 && threadIdx.x < 16)
        ((uint4*)sent_z)[threadIdx.x] = (uint4){0u, 0u, 0u, 0u};
    int g4 = blockIdx.x * 256 + threadIdx.x;  // float4 index; total 106496/4 = 26624
    if (g4 >= 26624) return;
    int e = g4 * 4;
    const float* src;
    int off;
    if (e < 98304) {
        int m = e >> 14;
        off = e & 16383;
        src = (m == 0) ? W1 : (m == 1) ? Ws1 : (m == 2) ? Wn1 : (m == 3) ? W2 : (m == 4) ? Ws2 : Wn2;
    } else {
        src = W3;
        off = e - 98304;
    }
    float4 v = *(const float4*)&src[off];
    ushort4 o = {f2bf(v.x), f2bf(v.y), f2bf(v.z), f2bf(v.w)};
    *(ushort4*)&out[e] = o;
}

// ---------------- CSR build: bucketed counting sort ----------------

__global__ __launch_bounds__(256) void hist_kernel(const int* __restrict__ dst, int* cnt, int E) {
    __shared__ int hh[NBUK];
    int t = threadIdx.x, blk = blockIdx.x;
    if (t < NBUK) hh[t] = 0;
    __syncthreads();
#pragma unroll
    for (int i = 0; i < EPB / 256; i++) {
        int e = blk * EPB + i * 256 + t;
        if (e < E) atomicAdd(&hh[dst[e] >> 9], 1);
    }
    __syncthreads();
    if (t < NBUK) cnt[t * NBLK + blk] = hh[t];
}

__global__ __launch_bounds__(512) void scan_blocks_kernel(int* cnt, int* btot) {
    __shared__ int s[512];
    int t = threadIdx.x, b = blockIdx.x;
    int v = (t < NBLK) ? cnt[b * NBLK + t] : 0;
    s[t] = v;
    __syncthreads();
#pragma unroll
    for (int off = 1; off < 512; off <<= 1) {
        int u = (t >= off) ? s[t - off] : 0;
        __syncthreads();
        s[t] += u;
        __syncthreads();
    }
    if (t < NBLK) cnt[b * NBLK + t] = s[t] - v;
    if (t == 511) btot[b] = s[511];
}

__global__ __launch_bounds__(256) void scan_buckets_kernel(const int* __restrict__ btot, int* bbase) {
    __shared__ int s[256];
    int t = threadIdx.x;
    int v = (t < NBUK) ? btot[t] : 0;
    s[t] = v;
    __syncthreads();
#pragma unroll
    for (int off = 1; off < 256; off <<= 1) {
        int u = (t >= off) ? s[t - off] : 0;
        __syncthreads();
        s[t] += u;
        __syncthreads();
    }
    if (t < NBUK) bbase[t] = s[t] - v;
}

__global__ __launch_bounds__(256) void scatter_kernel(const int* __restrict__ src,
                                                      const int* __restrict__ dst,
                                                      const int* __restrict__ cnt,
                                                      const int* __restrict__ bbase,
                                                      int* __restrict__ pairbuf, int E) {
    __shared__ int cur[NBUK];
    int t = threadIdx.x, blk = blockIdx.x;
    if (t < NBUK) cur[t] = cnt[t * NBLK + blk] + bbase[t];
    __syncthreads();
#pragma unroll
    for (int i = 0; i < EPB / 256; i++) {
        int e = blk * EPB + i * 256 + t;
        if (e < E) {
            int d = dst[e];
            int bk = d >> 9;
            int pos = atomicAdd(&cur[bk], 1);
            pairbuf[pos] = (src[e] << 9) | (d & 511);
        }
    }
}

// one block per bucket: degrees + x8-padded scan + csr fill (pre-scaled offsets) + pads
__global__ __launch_bounds__(256) void fill_kernel(const int* __restrict__ pairbuf,
                                                   const int* __restrict__ bbase,
                                                   const int* __restrict__ btot,
                                                   int* __restrict__ row_ptr,
                                                   int* __restrict__ ideg,
                                                   int* __restrict__ csr_src, int n) {
    __shared__ int deg[512], pstart[512], cur[512], stmp[256];
    int t = threadIdx.x, b = blockIdx.x;
    int estart = bbase[b], ecnt = btot[b];
    int cbase = estart + b * BSLACK;  // padded base (upper-bound slack)
    deg[t] = 0;
    deg[t + 256] = 0;
    __syncthreads();
    for (int i = t; i < ecnt; i += 256) atomicAdd(&deg[pairbuf[estart + i] & 511], 1);
    __syncthreads();
    int d0 = deg[2 * t], d1 = deg[2 * t + 1];
    int p0 = (d0 + 7) & ~7, p1 = (d1 + 7) & ~7;
    int pair = p0 + p1;
    stmp[t] = pair;
    __syncthreads();
#pragma unroll
    for (int off = 1; off < 256; off <<= 1) {
        int u = (t >= off) ? stmp[t - off] : 0;
        __syncthreads();
        stmp[t] += u;
        __syncthreads();
    }
    int excl = stmp[t] - pair;
    pstart[2 * t] = excl;
    pstart[2 * t + 1] = excl + p0;
    cur[2 * t] = excl;
    cur[2 * t + 1] = excl + p0;
    int g = b * 512 + 2 * t;
    if (g < n) { row_ptr[g] = cbase + excl; ideg[g] = d0; }
    if (g + 1 < n) { row_ptr[g + 1] = cbase + excl + p0; ideg[g + 1] = d1; }
    __syncthreads();
    for (int i = t; i < ecnt; i += 256) {
        int v = pairbuf[estart + i];
        int p = atomicAdd(&cur[v & 511], 1);
        csr_src[cbase + p] = (v >> 9) << 6;  // pre-scaled uint offset (src*64)
    }
    __syncthreads();
#pragma unroll
    for (int l2 = 0; l2 < 2; l2++) {
        int l = t + l2 * 256;
        int d = deg[l], pd = (d + 7) & ~7;
        for (int j = d; j < pd; j++) csr_src[cbase + pstart[l] + j] = NN << 6;  // sentinel
    }
}

// ---------------- gather-mean (bf16 rows, x8 unroll, pipelined indices) ------

__global__ __launch_bounds__(256) void gather_mean_kernel(const unsigned int* __restrict__ X32,
                                                          const int* __restrict__ row_ptr,
                                                          const int* __restrict__ ideg,
                                                          const int* __restrict__ csr_src,
                                                          unsigned int* __restrict__ Mout, int n) {
    int node = blockIdx.x * 4 + (threadIdx.x >> 6);
    if (node >= n) return;
    int lane = threadIdx.x & 63;
    int p = row_ptr[node];
    int deg = ideg[node];
    int pe = p + ((deg + 7) & ~7);  // x8-padded
    float inv = 1.0f / fmaxf((float)deg, 1.0f);
    float a0 = 0.f, a1 = 0.f, b0 = 0.f, b1 = 0.f;
    float c0 = 0.f, c1 = 0.f, e0 = 0.f, e1 = 0.f;
    if (p < pe) {
        int4 s0 = *(const int4*)&csr_src[p];
        int4 s1 = *(const int4*)&csr_src[p + 4];
        for (int q = p + 8; q < pe; q += 8) {
            int4 n0 = *(const int4*)&csr_src[q];      // prefetch next indices
            int4 n1 = *(const int4*)&csr_src[q + 4];
            unsigned u0 = X32[s0.x + lane];
            unsigned u1 = X32[s0.y + lane];
            unsigned u2 = X32[s0.z + lane];
            unsigned u3 = X32[s0.w + lane];
            unsigned u4 = X32[s1.x + lane];
            unsigned u5 = X32[s1.y + lane];
            unsigned u6 = X32[s1.z + lane];
            unsigned u7 = X32[s1.w + lane];
            a0 += lo16f(u0) + lo16f(u1);
            a1 += hi16f(u0) + hi16f(u1);
            b0 += lo16f(u2) + lo16f(u3);
            b1 += hi16f(u2) + hi16f(u3);
            c0 += lo16f(u4) + lo16f(u5);
            c1 += hi16f(u4) + hi16f(u5);
            e0 += lo16f(u6) + lo16f(u7);
            e1 += hi16f(u6) + hi16f(u7);
            s0 = n0;
            s1 = n1;
        }
        unsigned u0 = X32[s0.x + lane];
        unsigned u1 = X32[s0.y + lane];
        unsigned u2 = X32[s0.z + lane];
        unsigned u3 = X32[s0.w + lane];
        unsigned u4 = X32[s1.x + lane];
        unsigned u5 = X32[s1.y + lane];
        unsigned u6 = X32[s1.z + lane];
        unsigned u7 = X32[s1.w + lane];
        a0 += lo16f(u0) + lo16f(u1);
        a1 += hi16f(u0) + hi16f(u1);
        b0 += lo16f(u2) + lo16f(u3);
        b1 += hi16f(u2) + hi16f(u3);
        c0 += lo16f(u4) + lo16f(u5);
        c1 += hi16f(u4) + hi16f(u5);
        e0 += lo16f(u6) + lo16f(u7);
        e1 += hi16f(u6) + hi16f(u7);
    }
    float s0f = (a0 + b0) + (c0 + e0);
    float s1f = (a1 + b1) + (c1 + e1);
    unsigned o = (unsigned)f2bf(s0f * inv) | ((unsigned)f2bf(s1f * inv) << 16);
    Mout[(size_t)node * 64 + lane] = o;
}

// ---------------- standalone column stats (bf16 input) ----------------
// 256 blocks x 256 thr; thread owns 8 cols (one uint4) for 16 row-lanes.

__global__ __launch_bounds__(256) void colstats_kernel(const uint4* __restrict__ Y4, int M,
                                                       float* __restrict__ stats) {
    __shared__ float2 red[16 * 128];
    int tid = threadIdx.x;
    int c4 = tid & 15;   // uint4 index in row; cols c4*8 .. c4*8+7
    int rl = tid >> 4;   // row lane 0..15
    float s[8] = {0, 0, 0, 0, 0, 0, 0, 0};
    float q[8] = {0, 0, 0, 0, 0, 0, 0, 0};
    for (int r = blockIdx.x * 16 + rl; r < M; r += gridDim.x * 16) {
        uint4 u = Y4[(size_t)r * 16 + c4];
        float v;
        v = lo16f(u.x); s[0] += v; q[0] += v * v;
        v = hi16f(u.x); s[1] += v; q[1] += v * v;
        v = lo16f(u.y); s[2] += v; q[2] += v * v;
        v = hi16f(u.y); s[3] += v; q[3] += v * v;
        v = lo16f(u.z); s[4] += v; q[4] += v * v;
        v = hi16f(u.z); s[5] += v; q[5] += v * v;
        v = lo16f(u.w); s[6] += v; q[6] += v * v;
        v = hi16f(u.w); s[7] += v; q[7] += v * v;
    }
#pragma unroll
    for (int j = 0; j < 8; j++) red[rl * 128 + c4 * 8 + j] = make_float2(s[j], q[j]);
    __syncthreads();
    if (tid < 128) {
        float ss = 0.f, qq = 0.f;
#pragma unroll
        for (int i = 0; i < 16; i++) {
            float2 v = red[i * 128 + tid];
            ss += v.x;
            qq += v.y;
        }
        atomicAdd(&stats[tid], ss);
        atomicAdd(&stats[128 + tid], qq);
    }
}

// ---------------- batchnorm (finalize folded in) ----------------

__global__ __launch_bounds__(256) void bn_relu_kernel(const unsigned int* __restrict__ Yb,
                                                      const float* __restrict__ stats,
                                                      const float* __restrict__ gamma,
                                                      const float* __restrict__ beta,
                                                      unsigned int* __restrict__ X,
                                                      float invN, int n8) {
    int gid = blockIdx.x * 256 + threadIdx.x;
    if (gid >= n8) return;
    int c0 = (gid & 15) * 8;
    float4 s0 = *(const float4*)&stats[c0];
    float4 s1 = *(const float4*)&stats[c0 + 4];
    float4 q0 = *(const float4*)&stats[128 + c0];
    float4 q1 = *(const float4*)&stats[128 + c0 + 4];
    float4 g0 = *(const float4*)&gamma[c0];
    float4 g1 = *(const float4*)&gamma[c0 + 4];
    float4 b0 = *(const float4*)&beta[c0];
    float4 b1 = *(const float4*)&beta[c0 + 4];
    float sc[8], sh[8];
    float m;
    m = s0.x * invN; sc[0] = g0.x * rsqrtf(q0.x * invN - m * m + 1e-5f); sh[0] = b0.x - m * sc[0];
    m = s0.y * invN; sc[1] = g0.y * rsqrtf(q0.y * invN - m * m + 1e-5f); sh[1] = b0.y - m * sc[1];
    m = s0.z * invN; sc[2] = g0.z * rsqrtf(q0.z * invN - m * m + 1e-5f); sh[2] = b0.z - m * sc[2];
    m = s0.w * invN; sc[3] = g0.w * rsqrtf(q0.w * invN - m * m + 1e-5f); sh[3] = b0.w - m * sc[3];
    m = s1.x * invN; sc[4] = g1.x * rsqrtf(q1.x * invN - m * m + 1e-5f); sh[4] = b1.x - m * sc[4];
    m = s1.y * invN; sc[5] = g1.y * rsqrtf(q1.y * invN - m * m + 1e-5f); sh[5] = b1.y - m * sc[5];
    m = s1.z * invN; sc[6] = g1.z * rsqrtf(q1.z * invN - m * m + 1e-5f); sh[6] = b1.z - m * sc[6];
    m = s1.w * invN; sc[7] = g1.w * rsqrtf(q1.w * invN - m * m + 1e-5f); sh[7] = b1.w - m * sc[7];
    uint4 u = ((const uint4*)Yb)[gid];
    uint4 o;
    o.x = (unsigned)f2bf(fmaxf(fmaf(lo16f(u.x), sc[0], sh[0]), 0.f)) |
          ((unsigned)f2bf(fmaxf(fmaf(hi16f(u.x), sc[1], sh[1]), 0.f)) << 16);
    o.y = (unsigned)f2bf(fmaxf(fmaf(lo16f(u.y), sc[2], sh[2]), 0.f)) |
          ((unsigned)f2bf(fmaxf(fmaf(hi16f(u.y), sc[3], sh[3]), 0.f)) << 16);
    o.z = (unsigned)f2bf(fmaxf(fmaf(lo16f(u.z), sc[4], sh[4]), 0.f)) |
          ((unsigned)f2bf(fmaxf(fmaf(hi16f(u.z), sc[5], sh[5]), 0.f)) << 16);
    o.w = (unsigned)f2bf(fmaxf(fmaf(lo16f(u.w), sc[6], sh[6]), 0.f)) |
          ((unsigned)f2bf(fmaxf(fmaf(hi16f(u.w), sc[7], sh[7]), 0.f)) << 16);
    ((uint4*)X)[gid] = o;
}

// ---------------- MFMA GEMM, K=128: W in 32KB LDS (restaged) ----------------
// A1 fragments always prefetched at kernel entry (hidden under W staging +
// barrier). DUAL: pass-1 (A2) loads stay in-loop; launch_bounds(256,4).
// No STATS path anymore: all blocks retire at the C-write.

template <int NC, bool DUAL, bool RELU, bool OUTBF, bool BIAS, bool AF32>
__global__ __launch_bounds__(256, DUAL ? 4 : 1) void gemm_hyb(const void* A1v,
                                                const unsigned short* __restrict__ W1b,
                                                const unsigned short* __restrict__ A2,
                                                const unsigned short* __restrict__ W2b,
                                                const float* __restrict__ bias,
                                                void* __restrict__ Cout, int M) {
    constexpr int NG = NC / 16;
    constexpr int NPASS = DUAL ? 2 : 1;
    __shared__ __align__(16) char smem[NC * 256];  // one W tile

    const int tid = threadIdx.x;
    const int w = tid >> 6, lane = tid & 63;
    const int rl = lane & 15, kq = lane >> 4;
    const int m0 = blockIdx.x * 128;
    const int r0 = min(m0 + w * 32 + rl, M - 1);
    const int r1 = min(m0 + w * 32 + 16 + rl, M - 1);

    // ---- A1 prefetch: all pass-0 fragment loads before W staging ----
    float4 araw[2][8];   // AF32
    short8 apre[2][4];   // bf16
    if (AF32) {
        const float* Af = (const float*)A1v;
#pragma unroll
        for (int ks = 0; ks < 4; ks++) {
            const int ko = ks * 32 + kq * 8;
            araw[0][2 * ks]     = *(const float4*)&Af[(size_t)r0 * 128 + ko];
            araw[0][2 * ks + 1] = *(const float4*)&Af[(size_t)r0 * 128 + ko + 4];
            araw[1][2 * ks]     = *(const float4*)&Af[(size_t)r1 * 128 + ko];
            araw[1][2 * ks + 1] = *(const float4*)&Af[(size_t)r1 * 128 + ko + 4];
        }
    } else {
        const unsigned short* Ab = (const unsigned short*)A1v;
#pragma unroll
        for (int ks = 0; ks < 4; ks++) {
            const int ko = ks * 32 + kq * 8;
            apre[0][ks] = *(const short8*)&Ab[(size_t)r0 * 128 + ko];
            apre[1][ks] = *(const short8*)&Ab[(size_t)r1 * 128 + ko];
        }
    }

    f32x4 acc[2][NG];
#pragma unroll
    for (int mt = 0; mt < 2; mt++)
#pragma unroll
        for (int g = 0; g < NG; g++) acc[mt][g] = (f32x4){0.f, 0.f, 0.f, 0.f};

#pragma unroll
    for (int pass = 0; pass < NPASS; ++pass) {
        if (pass) __syncthreads();  // all waves done reading previous W tile
        {
            const unsigned short* W = pass ? W2b : W1b;
#pragma unroll
            for (int i = 0; i < NG; i++) {
                int iss = w * NG + i;             // 0 .. NC/4-1
                int row = iss * 4 + kq;           // 0 .. NC-1
                int slot = rl ^ (row & 7);
                GLOAD16((const char*)W + (size_t)row * 256 + (slot << 4), smem + iss * 1024);
            }
        }
        __syncthreads();
#pragma unroll
        for (int ks = 0; ks < 4; ks++) {
            const int ko = ks * 32 + kq * 8;
            short8 a0, a1;
            if (AF32) {
                float4 x0 = araw[0][2 * ks], x1 = araw[0][2 * ks + 1];
                float4 y0 = araw[1][2 * ks], y1 = araw[1][2 * ks + 1];
                a0 = (short8){(short)f2bf(x0.x), (short)f2bf(x0.y), (short)f2bf(x0.z), (short)f2bf(x0.w),
                              (short)f2bf(x1.x), (short)f2bf(x1.y), (short)f2bf(x1.z), (short)f2bf(x1.w)};
                a1 = (short8){(short)f2bf(y0.x), (short)f2bf(y0.y), (short)f2bf(y0.z), (short)f2bf(y0.w),
                              (short)f2bf(y1.x), (short)f2bf(y1.y), (short)f2bf(y1.z), (short)f2bf(y1.w)};
            } else if (pass == 0) {
                a0 = apre[0][ks];
                a1 = apre[1][ks];
            } else {
                a0 = *(const short8*)&A2[(size_t)r0 * 128 + ko];
                a1 = *(const short8*)&A2[(size_t)r1 * 128 + ko];
            }
#pragma unroll
            for (int g = 0; g < NG; g++) {
                int wr = g * 16 + rl;
                short8 bw = *(const short8*)(smem + wr * 256 + (((ks * 4 + kq) ^ (wr & 7)) << 4));
                acc[0][g] = __builtin_amdgcn_mfma_f32_16x16x32_bf16(a0, bw, acc[0][g], 0, 0, 0);
                acc[1][g] = __builtin_amdgcn_mfma_f32_16x16x32_bf16(a1, bw, acc[1][g], 0, 0, 0);
            }
        }
    }
    // epilogue: row = m0 + w*32 + mt*16 + kq*4 + r, col = g*16 + rl
    const int er = kq * 4;
#pragma unroll
    for (int mt = 0; mt < 2; mt++) {
        int rowb = m0 + w * 32 + mt * 16 + er;
#pragma unroll
        for (int g = 0; g < NG; g++) {
            int col = g * 16 + rl;
            float b = BIAS ? bias[col] : 0.f;
#pragma unroll
            for (int r = 0; r < 4; r++) {
                int row = rowb + r;
                if (row < M) {
                    float o = acc[mt][g][r] + b;
                    if (RELU) o = fmaxf(o, 0.f);
                    if (OUTBF)
                        ((unsigned short*)Cout)[(size_t)row * NC + col] = f2bf(o);
                    else
                        ((float*)Cout)[(size_t)row * NC + col] = o;
                }
            }
        }
    }
}

// ---------------- launch ----------------

extern "C" void kernel_launch(void* const* d_in, const int* in_sizes, int n_in,
                              void* d_out, int out_size, void* d_ws, size_t ws_size,
                              hipStream_t stream) {
    const float* h   = (const float*)d_in[0];
    const float* W1  = (const float*)d_in[1];
    const float* g1  = (const float*)d_in[3];
    const float* bt1 = (const float*)d_in[4];
    const float* Ws1 = (const float*)d_in[5];
    const float* Wn1 = (const float*)d_in[6];
    const float* bs1 = (const float*)d_in[7];
    const float* W2  = (const float*)d_in[8];
    const float* g2  = (const float*)d_in[10];
    const float* bt2 = (const float*)d_in[11];
    const float* Ws2 = (const float*)d_in[12];
    const float* Wn2 = (const float*)d_in[13];
    const float* bs2 = (const float*)d_in[14];
    const float* W3  = (const float*)d_in[15];
    const float* b3  = (const float*)d_in[16];
    const int* src   = (const int*)d_in[17];
    const int* dst   = (const int*)d_in[18];
    float* out = (float*)d_out;

    const int N = NN, E = NE;
    char* ws = (char*)d_ws;
    // Xb: [N+1,128] bf16 (row N = zero sentinel); Yb: [N,128] bf16; Mb: [N,128] bf16
    unsigned short* Xb = (unsigned short*)ws;                   // 25,600,256 B
    unsigned short* Yb = (unsigned short*)(ws + 25600512);      // 25.6 MB
    unsigned int* Mb = (unsigned int*)(ws + 51201024);          // 25.6 MB
    char* tail = ws + 76801536;
    float* stats1 = (float*)tail;        // [256]
    float* stats2 = stats1 + 256;        // [256]
    unsigned short* Wb = (unsigned short*)(stats2 + 256);  // 106496 bf16
    const unsigned short* Wb1  = Wb;
    const unsigned short* Wbs1 = Wb + 16384;
    const unsigned short* Wbn1 = Wb + 32768;
    const unsigned short* Wb2  = Wb + 49152;
    const unsigned short* Wbs2 = Wb + 65536;
    const unsigned short* Wbn2 = Wb + 81920;
    const unsigned short* Wb3  = Wb + 98304;

    // CSR scratch in d_out (dead before final GEMM overwrites it)
    int* ideg    = (int*)d_out;            // [N]
    int* row_ptr = ideg + N;               // [N] padded starts
    int* csr_src = row_ptr + N;            // [CSRCAP] pre-scaled offsets
    int* pairbuf = csr_src + CSRCAP;       // [E]
    int* cnt     = pairbuf + E;            // [NBUK*NBLK]
    int* btot    = cnt + NBUK * NBLK;      // [NBUK]
    int* bbase   = btot + NBUK;            // [NBUK]

    const int gm = (N + 127) / 128;       // 782 GEMM blocks
    const int nw8 = (N * 16 + 255) / 256; // bf16x8 elementwise grid
    const int gg = (N + 3) / 4;           // gather: 4 nodes per block
    const float invN = 1.0f / N;

    // conversions (wcvt also zeroes stats1/2 and the sentinel row) + CSR build
    wcvt_kernel<<<104, 256, 0, stream>>>(W1, Ws1, Wn1, W2, Ws2, Wn2, W3, Wb,
                                         stats1, (unsigned int*)(Xb + (size_t)N * 128));
    hist_kernel<<<NBLK, 256, 0, stream>>>(dst, cnt, E);
    scan_blocks_kernel<<<NBUK, 512, 0, stream>>>(cnt, btot);
    scan_buckets_kernel<<<1, 256, 0, stream>>>(btot, bbase);
    scatter_kernel<<<NBLK, 256, 0, stream>>>(src, dst, cnt, bbase, pairbuf, E);
    fill_kernel<<<NBUK, 256, 0, stream>>>(pairbuf, bbase, btot, row_ptr, ideg, csr_src, N);

    // dense1 (A fp32 = h; bias cancels in BN) + colstats + BN + ReLU
    gemm_hyb<128, false, false, true, false, true>
        <<<gm, 256, 0, stream>>>(h, Wb1, nullptr, nullptr, nullptr, Yb, N);
    colstats_kernel<<<256, 256, 0, stream>>>((const uint4*)Yb, N, stats1);
    bn_relu_kernel<<<nw8, 256, 0, stream>>>((const unsigned int*)Yb, stats1, g1, bt1,
                                            (unsigned int*)Xb, invN, N * 16);

    // SAGE 1
    gather_mean_kernel<<<gg, 256, 0, stream>>>((const unsigned int*)Xb, row_ptr, ideg, csr_src,
                                               (unsigned int*)Mb, N);
    gemm_hyb<128, true, true, true, true, false>
        <<<gm, 256, 0, stream>>>(Xb, Wbs1, (const unsigned short*)Mb, Wbn1, bs1, Xb, N);

    // dense2 + colstats + BN + ReLU
    gemm_hyb<128, false, false, true, false, false>
        <<<gm, 256, 0, stream>>>(Xb, Wb2, nullptr, nullptr, nullptr, Yb, N);
    colstats_kernel<<<256, 256, 0, stream>>>((const uint4*)Yb, N, stats2);
    bn_relu_kernel<<<nw8, 256, 0, stream>>>((const unsigned int*)Yb, stats2, g2, bt2,
                                            (unsigned int*)Xb, invN, N * 16);

    // SAGE 2
    gather_mean_kernel<<<gg, 256, 0, stream>>>((const unsigned int*)Xb, row_ptr, ideg, csr_src,
                                               (unsigned int*)Mb, N);
    gemm_hyb<128, true, true, true, true, false>
        <<<gm, 256, 0, stream>>>(Xb, Wbs2, (const unsigned short*)Mb, Wbn2, bs2, Xb, N);

    // output layer
    gemm_hyb<64, false, true, false, true, false>
        <<<gm, 256, 0, stream>>>(Xb, Wb3, nullptr, nullptr, b3, out, N);
}

// Round 18
// 253.134 us; speedup vs baseline: 1.0111x; 1.0111x over previous
//
#include <hip/hip_runtime.h>
#include <hip/hip_bf16.h>
#include <cstddef>

// GNN: dense1+BN+ReLU -> SAGE(mean) -> dense2+BN+ReLU -> SAGE(mean) -> dense_out
// FINAL (= round 16, validated best 253.2us): round-17's stats de-fusion was
// neutral-negative and is reverted. Structure:
//   - bf16 activations/weights (one wcvt pass; fused stats/sentinel zeroing)
//   - CSR via bucketed counting sort (hist/scan/scan/scatter/fill), x8-padded
//     rows, pre-scaled offsets, sentinel zero row
//   - gather-mean: wave/node, x8 unroll, software-pipelined index loads
//   - GEMM: MFMA 16x16x32, W in 32KB LDS (swizzled global_load_lds, restaged
//     for DUAL), A1 fragments prefetched to regs, fused BN-stats in epilogue
//   - BN finalize folded into bn_relu (stats->scale/shift per thread)

#define NN 100000
#define NE 800000
#define EPB 2048                     // edges per hist/scatter block
#define NBLK ((NE + EPB - 1) / EPB)  // 391
#define NBUK ((NN + 511) / 512)      // 196 buckets of 512 nodes
#define BSLACK (512 * 7)             // max pad slack per bucket (x8 padding)
#define CSRCAP (NE + NBUK * BSLACK)  // padded csr upper bound

typedef __attribute__((ext_vector_type(8))) short short8;
typedef __attribute__((ext_vector_type(4))) float f32x4;

__device__ inline unsigned short f2bf(float f) {
    unsigned int u = __float_as_uint(f);
    u += 0x7fff + ((u >> 16) & 1);   // round-to-nearest-even
    return (unsigned short)(u >> 16);
}
__device__ inline float lo16f(unsigned u) { return __uint_as_float(u << 16); }
__device__ inline float hi16f(unsigned u) { return __uint_as_float(u & 0xffff0000u); }

#define GLOAD16(gp, lp)                                                              \
    __builtin_amdgcn_global_load_lds((const __attribute__((address_space(1))) unsigned int*)(gp), \
                                     (__attribute__((address_space(3))) unsigned int*)(lp), 16, 0, 0)

// ---------------- conversions (+ fused stats/sentinel zeroing) ----------------

__global__ __launch_bounds__(256) void wcvt_kernel(const float* W1, const float* Ws1, const float* Wn1,
                                                   const float* W2, const float* Ws2, const float* Wn2,
                                                   const float* W3, unsigned short* out,
                                                   float* stats_z, unsigned int* sent_z) {
    // block 0: zero both layers' stats (512 floats); block 1: zero sentinel row (256B)
    if (blockIdx.x == 0 && threadIdx.x < 128)
        ((float4*)stats_z)[threadIdx.x] = (float4){0.f, 0.f, 0.f, 0.f};
    if (blockIdx.x == 1 && threadIdx.x < 16)
        ((uint4*)sent_z)[threadIdx.x] = (uint4){0u, 0u, 0u, 0u};
    int g4 = blockIdx.x * 256 + threadIdx.x;  // float4 index; total 106496/4 = 26624
    if (g4 >= 26624) return;
    int e = g4 * 4;
    const float* src;
    int off;
    if (e < 98304) {
        int m = e >> 14;
        off = e & 16383;
        src = (m == 0) ? W1 : (m == 1) ? Ws1 : (m == 2) ? Wn1 : (m == 3) ? W2 : (m == 4) ? Ws2 : Wn2;
    } else {
        src = W3;
        off = e - 98304;
    }
    float4 v = *(const float4*)&src[off];
    ushort4 o = {f2bf(v.x), f2bf(v.y), f2bf(v.z), f2bf(v.w)};
    *(ushort4*)&out[e] = o;
}

// ---------------- CSR build: bucketed counting sort ----------------

__global__ __launch_bounds__(256) void hist_kernel(const int* __restrict__ dst, int* cnt, int E) {
    __shared__ int hh[NBUK];
    int t = threadIdx.x, blk = blockIdx.x;
    if (t < NBUK) hh[t] = 0;
    __syncthreads();
#pragma unroll
    for (int i = 0; i < EPB / 256; i++) {
        int e = blk * EPB + i * 256 + t;
        if (e < E) atomicAdd(&hh[dst[e] >> 9], 1);
    }
    __syncthreads();
    if (t < NBUK) cnt[t * NBLK + blk] = hh[t];
}

__global__ __launch_bounds__(512) void scan_blocks_kernel(int* cnt, int* btot) {
    __shared__ int s[512];
    int t = threadIdx.x, b = blockIdx.x;
    int v = (t < NBLK) ? cnt[b * NBLK + t] : 0;
    s[t] = v;
    __syncthreads();
#pragma unroll
    for (int off = 1; off < 512; off <<= 1) {
        int u = (t >= off) ? s[t - off] : 0;
        __syncthreads();
        s[t] += u;
        __syncthreads();
    }
    if (t < NBLK) cnt[b * NBLK + t] = s[t] - v;
    if (t == 511) btot[b] = s[511];
}

__global__ __launch_bounds__(256) void scan_buckets_kernel(const int* __restrict__ btot, int* bbase) {
    __shared__ int s[256];
    int t = threadIdx.x;
    int v = (t < NBUK) ? btot[t] : 0;
    s[t] = v;
    __syncthreads();
#pragma unroll
    for (int off = 1; off < 256; off <<= 1) {
        int u = (t >= off) ? s[t - off] : 0;
        __syncthreads();
        s[t] += u;
        __syncthreads();
    }
    if (t < NBUK) bbase[t] = s[t] - v;
}

__global__ __launch_bounds__(256) void scatter_kernel(const int* __restrict__ src,
                                                      const int* __restrict__ dst,
                                                      const int* __restrict__ cnt,
                                                      const int* __restrict__ bbase,
                                                      int* __restrict__ pairbuf, int E) {
    __shared__ int cur[NBUK];
    int t = threadIdx.x, blk = blockIdx.x;
    if (t < NBUK) cur[t] = cnt[t * NBLK + blk] + bbase[t];
    __syncthreads();
#pragma unroll
    for (int i = 0; i < EPB / 256; i++) {
        int e = blk * EPB + i * 256 + t;
        if (e < E) {
            int d = dst[e];
            int bk = d >> 9;
            int pos = atomicAdd(&cur[bk], 1);
            pairbuf[pos] = (src[e] << 9) | (d & 511);
        }
    }
}

// one block per bucket: degrees + x8-padded scan + csr fill (pre-scaled offsets) + pads
__global__ __launch_bounds__(256) void fill_kernel(const int* __restrict__ pairbuf,
                                                   const int* __restrict__ bbase,
                                                   const int* __restrict__ btot,
                                                   int* __restrict__ row_ptr,
                                                   int* __restrict__ ideg,
                                                   int* __restrict__ csr_src, int n) {
    __shared__ int deg[512], pstart[512], cur[512], stmp[256];
    int t = threadIdx.x, b = blockIdx.x;
    int estart = bbase[b], ecnt = btot[b];
    int cbase = estart + b * BSLACK;  // padded base (upper-bound slack)
    deg[t] = 0;
    deg[t + 256] = 0;
    __syncthreads();
    for (int i = t; i < ecnt; i += 256) atomicAdd(&deg[pairbuf[estart + i] & 511], 1);
    __syncthreads();
    int d0 = deg[2 * t], d1 = deg[2 * t + 1];
    int p0 = (d0 + 7) & ~7, p1 = (d1 + 7) & ~7;
    int pair = p0 + p1;
    stmp[t] = pair;
    __syncthreads();
#pragma unroll
    for (int off = 1; off < 256; off <<= 1) {
        int u = (t >= off) ? stmp[t - off] : 0;
        __syncthreads();
        stmp[t] += u;
        __syncthreads();
    }
    int excl = stmp[t] - pair;
    pstart[2 * t] = excl;
    pstart[2 * t + 1] = excl + p0;
    cur[2 * t] = excl;
    cur[2 * t + 1] = excl + p0;
    int g = b * 512 + 2 * t;
    if (g < n) { row_ptr[g] = cbase + excl; ideg[g] = d0; }
    if (g + 1 < n) { row_ptr[g + 1] = cbase + excl + p0; ideg[g + 1] = d1; }
    __syncthreads();
    for (int i = t; i < ecnt; i += 256) {
        int v = pairbuf[estart + i];
        int p = atomicAdd(&cur[v & 511], 1);
        csr_src[cbase + p] = (v >> 9) << 6;  // pre-scaled uint offset (src*64)
    }
    __syncthreads();
#pragma unroll
    for (int l2 = 0; l2 < 2; l2++) {
        int l = t + l2 * 256;
        int d = deg[l], pd = (d + 7) & ~7;
        for (int j = d; j < pd; j++) csr_src[cbase + pstart[l] + j] = NN << 6;  // sentinel
    }
}

// ---------------- gather-mean (bf16 rows, x8 unroll, pipelined indices) ------
// one 64-lane wave per node, uint per lane; iteration i's row loads use index
// registers fetched in iteration i-1 (steady state has no index->row chain).

__global__ __launch_bounds__(256) void gather_mean_kernel(const unsigned int* __restrict__ X32,
                                                          const int* __restrict__ row_ptr,
                                                          const int* __restrict__ ideg,
                                                          const int* __restrict__ csr_src,
                                                          unsigned int* __restrict__ Mout, int n) {
    int node = blockIdx.x * 4 + (threadIdx.x >> 6);
    if (node >= n) return;
    int lane = threadIdx.x & 63;
    int p = row_ptr[node];
    int deg = ideg[node];
    int pe = p + ((deg + 7) & ~7);  // x8-padded
    float inv = 1.0f / fmaxf((float)deg, 1.0f);
    float a0 = 0.f, a1 = 0.f, b0 = 0.f, b1 = 0.f;
    float c0 = 0.f, c1 = 0.f, e0 = 0.f, e1 = 0.f;
    if (p < pe) {
        int4 s0 = *(const int4*)&csr_src[p];
        int4 s1 = *(const int4*)&csr_src[p + 4];
        for (int q = p + 8; q < pe; q += 8) {
            int4 n0 = *(const int4*)&csr_src[q];      // prefetch next indices
            int4 n1 = *(const int4*)&csr_src[q + 4];
            unsigned u0 = X32[s0.x + lane];
            unsigned u1 = X32[s0.y + lane];
            unsigned u2 = X32[s0.z + lane];
            unsigned u3 = X32[s0.w + lane];
            unsigned u4 = X32[s1.x + lane];
            unsigned u5 = X32[s1.y + lane];
            unsigned u6 = X32[s1.z + lane];
            unsigned u7 = X32[s1.w + lane];
            a0 += lo16f(u0) + lo16f(u1);
            a1 += hi16f(u0) + hi16f(u1);
            b0 += lo16f(u2) + lo16f(u3);
            b1 += hi16f(u2) + hi16f(u3);
            c0 += lo16f(u4) + lo16f(u5);
            c1 += hi16f(u4) + hi16f(u5);
            e0 += lo16f(u6) + lo16f(u7);
            e1 += hi16f(u6) + hi16f(u7);
            s0 = n0;
            s1 = n1;
        }
        unsigned u0 = X32[s0.x + lane];
        unsigned u1 = X32[s0.y + lane];
        unsigned u2 = X32[s0.z + lane];
        unsigned u3 = X32[s0.w + lane];
        unsigned u4 = X32[s1.x + lane];
        unsigned u5 = X32[s1.y + lane];
        unsigned u6 = X32[s1.z + lane];
        unsigned u7 = X32[s1.w + lane];
        a0 += lo16f(u0) + lo16f(u1);
        a1 += hi16f(u0) + hi16f(u1);
        b0 += lo16f(u2) + lo16f(u3);
        b1 += hi16f(u2) + hi16f(u3);
        c0 += lo16f(u4) + lo16f(u5);
        c1 += hi16f(u4) + hi16f(u5);
        e0 += lo16f(u6) + lo16f(u7);
        e1 += hi16f(u6) + hi16f(u7);
    }
    float s0f = (a0 + b0) + (c0 + e0);
    float s1f = (a1 + b1) + (c1 + e1);
    unsigned o = (unsigned)f2bf(s0f * inv) | ((unsigned)f2bf(s1f * inv) << 16);
    Mout[(size_t)node * 64 + lane] = o;
}

// ---------------- batchnorm (finalize folded in) ----------------

__global__ __launch_bounds__(256) void bn_relu_kernel(const unsigned int* __restrict__ Yb,
                                                      const float* __restrict__ stats,
                                                      const float* __restrict__ gamma,
                                                      const float* __restrict__ beta,
                                                      unsigned int* __restrict__ X,
                                                      float invN, int n8) {
    int gid = blockIdx.x * 256 + threadIdx.x;
    if (gid >= n8) return;
    int c0 = (gid & 15) * 8;
    float4 s0 = *(const float4*)&stats[c0];
    float4 s1 = *(const float4*)&stats[c0 + 4];
    float4 q0 = *(const float4*)&stats[128 + c0];
    float4 q1 = *(const float4*)&stats[128 + c0 + 4];
    float4 g0 = *(const float4*)&gamma[c0];
    float4 g1 = *(const float4*)&gamma[c0 + 4];
    float4 b0 = *(const float4*)&beta[c0];
    float4 b1 = *(const float4*)&beta[c0 + 4];
    float sc[8], sh[8];
    float m;
    m = s0.x * invN; sc[0] = g0.x * rsqrtf(q0.x * invN - m * m + 1e-5f); sh[0] = b0.x - m * sc[0];
    m = s0.y * invN; sc[1] = g0.y * rsqrtf(q0.y * invN - m * m + 1e-5f); sh[1] = b0.y - m * sc[1];
    m = s0.z * invN; sc[2] = g0.z * rsqrtf(q0.z * invN - m * m + 1e-5f); sh[2] = b0.z - m * sc[2];
    m = s0.w * invN; sc[3] = g0.w * rsqrtf(q0.w * invN - m * m + 1e-5f); sh[3] = b0.w - m * sc[3];
    m = s1.x * invN; sc[4] = g1.x * rsqrtf(q1.x * invN - m * m + 1e-5f); sh[4] = b1.x - m * sc[4];
    m = s1.y * invN; sc[5] = g1.y * rsqrtf(q1.y * invN - m * m + 1e-5f); sh[5] = b1.y - m * sc[5];
    m = s1.z * invN; sc[6] = g1.z * rsqrtf(q1.z * invN - m * m + 1e-5f); sh[6] = b1.z - m * sc[6];
    m = s1.w * invN; sc[7] = g1.w * rsqrtf(q1.w * invN - m * m + 1e-5f); sh[7] = b1.w - m * sc[7];
    uint4 u = ((const uint4*)Yb)[gid];
    uint4 o;
    o.x = (unsigned)f2bf(fmaxf(fmaf(lo16f(u.x), sc[0], sh[0]), 0.f)) |
          ((unsigned)f2bf(fmaxf(fmaf(hi16f(u.x), sc[1], sh[1]), 0.f)) << 16);
    o.y = (unsigned)f2bf(fmaxf(fmaf(lo16f(u.y), sc[2], sh[2]), 0.f)) |
          ((unsigned)f2bf(fmaxf(fmaf(hi16f(u.y), sc[3], sh[3]), 0.f)) << 16);
    o.z = (unsigned)f2bf(fmaxf(fmaf(lo16f(u.z), sc[4], sh[4]), 0.f)) |
          ((unsigned)f2bf(fmaxf(fmaf(hi16f(u.z), sc[5], sh[5]), 0.f)) << 16);
    o.w = (unsigned)f2bf(fmaxf(fmaf(lo16f(u.w), sc[6], sh[6]), 0.f)) |
          ((unsigned)f2bf(fmaxf(fmaf(hi16f(u.w), sc[7], sh[7]), 0.f)) << 16);
    ((uint4*)X)[gid] = o;
}

// ---------------- MFMA GEMM, K=128: W in 32KB LDS (restaged) ----------------
// A1 fragments always prefetched at kernel entry (hidden under W staging +
// barrier). DUAL: pass-1 (A2) loads stay in-loop; launch_bounds(256,4).

template <int NC, bool DUAL, bool RELU, bool STATS, bool OUTBF, bool BIAS, bool AF32>
__global__ __launch_bounds__(256, DUAL ? 4 : 1) void gemm_hyb(const void* A1v,
                                                const unsigned short* __restrict__ W1b,
                                                const unsigned short* __restrict__ A2,
                                                const unsigned short* __restrict__ W2b,
                                                const float* __restrict__ bias,
                                                void* __restrict__ Cout,
                                                float* __restrict__ stats, int M) {
    constexpr int NG = NC / 16;
    constexpr int NPASS = DUAL ? 2 : 1;
    __shared__ __align__(16) char smem[NC * 256];  // one W tile

    const int tid = threadIdx.x;
    const int w = tid >> 6, lane = tid & 63;
    const int rl = lane & 15, kq = lane >> 4;
    const int m0 = blockIdx.x * 128;
    const int r0 = min(m0 + w * 32 + rl, M - 1);
    const int r1 = min(m0 + w * 32 + 16 + rl, M - 1);

    // ---- A1 prefetch: all pass-0 fragment loads before W staging ----
    float4 araw[2][8];   // AF32
    short8 apre[2][4];   // bf16
    if (AF32) {
        const float* Af = (const float*)A1v;
#pragma unroll
        for (int ks = 0; ks < 4; ks++) {
            const int ko = ks * 32 + kq * 8;
            araw[0][2 * ks]     = *(const float4*)&Af[(size_t)r0 * 128 + ko];
            araw[0][2 * ks + 1] = *(const float4*)&Af[(size_t)r0 * 128 + ko + 4];
            araw[1][2 * ks]     = *(const float4*)&Af[(size_t)r1 * 128 + ko];
            araw[1][2 * ks + 1] = *(const float4*)&Af[(size_t)r1 * 128 + ko + 4];
        }
    } else {
        const unsigned short* Ab = (const unsigned short*)A1v;
#pragma unroll
        for (int ks = 0; ks < 4; ks++) {
            const int ko = ks * 32 + kq * 8;
            apre[0][ks] = *(const short8*)&Ab[(size_t)r0 * 128 + ko];
            apre[1][ks] = *(const short8*)&Ab[(size_t)r1 * 128 + ko];
        }
    }

    f32x4 acc[2][NG];
#pragma unroll
    for (int mt = 0; mt < 2; mt++)
#pragma unroll
        for (int g = 0; g < NG; g++) acc[mt][g] = (f32x4){0.f, 0.f, 0.f, 0.f};

#pragma unroll
    for (int pass = 0; pass < NPASS; ++pass) {
        if (pass) __syncthreads();  // all waves done reading previous W tile
        {
            const unsigned short* W = pass ? W2b : W1b;
#pragma unroll
            for (int i = 0; i < NG; i++) {
                int iss = w * NG + i;             // 0 .. NC/4-1
                int row = iss * 4 + kq;           // 0 .. NC-1
                int slot = rl ^ (row & 7);
                GLOAD16((const char*)W + (size_t)row * 256 + (slot << 4), smem + iss * 1024);
            }
        }
        __syncthreads();
#pragma unroll
        for (int ks = 0; ks < 4; ks++) {
            const int ko = ks * 32 + kq * 8;
            short8 a0, a1;
            if (AF32) {
                float4 x0 = araw[0][2 * ks], x1 = araw[0][2 * ks + 1];
                float4 y0 = araw[1][2 * ks], y1 = araw[1][2 * ks + 1];
                a0 = (short8){(short)f2bf(x0.x), (short)f2bf(x0.y), (short)f2bf(x0.z), (short)f2bf(x0.w),
                              (short)f2bf(x1.x), (short)f2bf(x1.y), (short)f2bf(x1.z), (short)f2bf(x1.w)};
                a1 = (short8){(short)f2bf(y0.x), (short)f2bf(y0.y), (short)f2bf(y0.z), (short)f2bf(y0.w),
                              (short)f2bf(y1.x), (short)f2bf(y1.y), (short)f2bf(y1.z), (short)f2bf(y1.w)};
            } else if (pass == 0) {
                a0 = apre[0][ks];
                a1 = apre[1][ks];
            } else {
                a0 = *(const short8*)&A2[(size_t)r0 * 128 + ko];
                a1 = *(const short8*)&A2[(size_t)r1 * 128 + ko];
            }
#pragma unroll
            for (int g = 0; g < NG; g++) {
                int wr = g * 16 + rl;
                short8 bw = *(const short8*)(smem + wr * 256 + (((ks * 4 + kq) ^ (wr & 7)) << 4));
                acc[0][g] = __builtin_amdgcn_mfma_f32_16x16x32_bf16(a0, bw, acc[0][g], 0, 0, 0);
                acc[1][g] = __builtin_amdgcn_mfma_f32_16x16x32_bf16(a1, bw, acc[1][g], 0, 0, 0);
            }
        }
    }
    // epilogue: row = m0 + w*32 + mt*16 + kq*4 + r, col = g*16 + rl
    const int er = kq * 4;
#pragma unroll
    for (int mt = 0; mt < 2; mt++) {
        int rowb = m0 + w * 32 + mt * 16 + er;
#pragma unroll
        for (int g = 0; g < NG; g++) {
            int col = g * 16 + rl;
            float b = BIAS ? bias[col] : 0.f;
#pragma unroll
            for (int r = 0; r < 4; r++) {
                int row = rowb + r;
                if (row < M) {
                    float o = acc[mt][g][r] + b;
                    if (RELU) o = fmaxf(o, 0.f);
                    if (OUTBF)
                        ((unsigned short*)Cout)[(size_t)row * NC + col] = f2bf(o);
                    else
                        ((float*)Cout)[(size_t)row * NC + col] = o;
                }
            }
        }
    }
    if constexpr (STATS) {
        __syncthreads();  // done with W LDS -> reuse as reduce buffer (16KB <= 32KB)
        float2* part = (float2*)smem;
        const int widx = w * 4 + kq;
#pragma unroll
        for (int g = 0; g < NG; g++) {
            float s = 0.f, q = 0.f;
#pragma unroll
            for (int mt = 0; mt < 2; mt++) {
                int rowb = m0 + w * 32 + mt * 16 + er;
#pragma unroll
                for (int r = 0; r < 4; r++)
                    if (rowb + r < M) {
                        float v = acc[mt][g][r];
                        s += v;
                        q += v * v;
                    }
            }
            part[widx * 128 + g * 16 + rl] = make_float2(s, q);
        }
        __syncthreads();
        if (tid < 128) {
            float s = 0.f, q = 0.f;
#pragma unroll
            for (int i = 0; i < 16; i++) {
                float2 v = part[i * 128 + tid];
                s += v.x;
                q += v.y;
            }
            atomicAdd(&stats[tid], s);
            atomicAdd(&stats[128 + tid], q);
        }
    }
}

// ---------------- launch ----------------

extern "C" void kernel_launch(void* const* d_in, const int* in_sizes, int n_in,
                              void* d_out, int out_size, void* d_ws, size_t ws_size,
                              hipStream_t stream) {
    const float* h   = (const float*)d_in[0];
    const float* W1  = (const float*)d_in[1];
    const float* g1  = (const float*)d_in[3];
    const float* bt1 = (const float*)d_in[4];
    const float* Ws1 = (const float*)d_in[5];
    const float* Wn1 = (const float*)d_in[6];
    const float* bs1 = (const float*)d_in[7];
    const float* W2  = (const float*)d_in[8];
    const float* g2  = (const float*)d_in[10];
    const float* bt2 = (const float*)d_in[11];
    const float* Ws2 = (const float*)d_in[12];
    const float* Wn2 = (const float*)d_in[13];
    const float* bs2 = (const float*)d_in[14];
    const float* W3  = (const float*)d_in[15];
    const float* b3  = (const float*)d_in[16];
    const int* src   = (const int*)d_in[17];
    const int* dst   = (const int*)d_in[18];
    float* out = (float*)d_out;

    const int N = NN, E = NE;
    char* ws = (char*)d_ws;
    // Xb: [N+1,128] bf16 (row N = zero sentinel); Yb: [N,128] bf16; Mb: [N,128] bf16
    unsigned short* Xb = (unsigned short*)ws;                   // 25,600,256 B
    unsigned short* Yb = (unsigned short*)(ws + 25600512);      // 25.6 MB
    unsigned int* Mb = (unsigned int*)(ws + 51201024);          // 25.6 MB
    char* tail = ws + 76801536;
    float* stats1 = (float*)tail;        // [256]
    float* stats2 = stats1 + 256;        // [256]
    unsigned short* Wb = (unsigned short*)(stats2 + 256);  // 106496 bf16
    const unsigned short* Wb1  = Wb;
    const unsigned short* Wbs1 = Wb + 16384;
    const unsigned short* Wbn1 = Wb + 32768;
    const unsigned short* Wb2  = Wb + 49152;
    const unsigned short* Wbs2 = Wb + 65536;
    const unsigned short* Wbn2 = Wb + 81920;
    const unsigned short* Wb3  = Wb + 98304;

    // CSR scratch in d_out (dead before final GEMM overwrites it)
    int* ideg    = (int*)d_out;            // [N]
    int* row_ptr = ideg + N;               // [N] padded starts
    int* csr_src = row_ptr + N;            // [CSRCAP] pre-scaled offsets
    int* pairbuf = csr_src + CSRCAP;       // [E]
    int* cnt     = pairbuf + E;            // [NBUK*NBLK]
    int* btot    = cnt + NBUK * NBLK;      // [NBUK]
    int* bbase   = btot + NBUK;            // [NBUK]

    const int gm = (N + 127) / 128;       // 782 GEMM blocks
    const int nw8 = (N * 16 + 255) / 256; // bf16x8 elementwise grid
    const int gg = (N + 3) / 4;           // gather: 4 nodes per block
    const float invN = 1.0f / N;

    // conversions (wcvt also zeroes stats1/2 and the sentinel row) + CSR build
    wcvt_kernel<<<104, 256, 0, stream>>>(W1, Ws1, Wn1, W2, Ws2, Wn2, W3, Wb,
                                         stats1, (unsigned int*)(Xb + (size_t)N * 128));
    hist_kernel<<<NBLK, 256, 0, stream>>>(dst, cnt, E);
    scan_blocks_kernel<<<NBUK, 512, 0, stream>>>(cnt, btot);
    scan_buckets_kernel<<<1, 256, 0, stream>>>(btot, bbase);
    scatter_kernel<<<NBLK, 256, 0, stream>>>(src, dst, cnt, bbase, pairbuf, E);
    fill_kernel<<<NBUK, 256, 0, stream>>>(pairbuf, bbase, btot, row_ptr, ideg, csr_src, N);

    // dense1 (A fp32 = h, stats fused; bias cancels in BN) + BN + ReLU
    gemm_hyb<128, false, false, true, true, false, true>
        <<<gm, 256, 0, stream>>>(h, Wb1, nullptr, nullptr, nullptr, Yb, stats1, N);
    bn_relu_kernel<<<nw8, 256, 0, stream>>>((const unsigned int*)Yb, stats1, g1, bt1,
                                            (unsigned int*)Xb, invN, N * 16);

    // SAGE 1
    gather_mean_kernel<<<gg, 256, 0, stream>>>((const unsigned int*)Xb, row_ptr, ideg, csr_src,
                                               (unsigned int*)Mb, N);
    gemm_hyb<128, true, true, false, true, true, false>
        <<<gm, 256, 0, stream>>>(Xb, Wbs1, (const unsigned short*)Mb, Wbn1, bs1, Xb, nullptr, N);

    // dense2 + BN + ReLU
    gemm_hyb<128, false, false, true, true, false, false>
        <<<gm, 256, 0, stream>>>(Xb, Wb2, nullptr, nullptr, nullptr, Yb, stats2, N);
    bn_relu_kernel<<<nw8, 256, 0, stream>>>((const unsigned int*)Yb, stats2, g2, bt2,
                                            (unsigned int*)Xb, invN, N * 16);

    // SAGE 2
    gather_mean_kernel<<<gg, 256, 0, stream>>>((const unsigned int*)Xb, row_ptr, ideg, csr_src,
                                               (unsigned int*)Mb, N);
    gemm_hyb<128, true, true, false, true, true, false>
        <<<gm, 256, 0, stream>>>(Xb, Wbs2, (const unsigned short*)Mb, Wbn2, bs2, Xb, nullptr, N);

    // output layer
    gemm_hyb<64, false, true, false, false, true, false>
        <<<gm, 256, 0, stream>>>(Xb, Wb3, nullptr, nullptr, b3, out, nullptr, N);
}